// Round 1
// baseline (411.334 us; speedup 1.0000x reference)
//
#include <hip/hip_runtime.h>

#define NB 8
#define NN 128
#define ND 64
#define NE 3
#define NH 256
#define NOUT 64

// ---------------- Kernel 1: P/Q precompute ----------------
// P[b,e,i,h] = sum_d ns[b,i,d] * We1[e,d,h]
// Q[b,e,i,h] = sum_d ns[b,i,d] * We1[e,D+d,h] + be1[e,h]
#define IT 16
__global__ __launch_bounds__(256) void pq_kernel(
    const float* __restrict__ ns,
    const float* __restrict__ We1,
    const float* __restrict__ be1,
    float* __restrict__ P, float* __restrict__ Q)
{
    const int blk = blockIdx.x;
    const int itile = blk & 7;            // N/IT = 8
    const int e = (blk >> 3) % NE;
    const int b = blk / (8 * NE);
    const int i0 = itile * IT;
    __shared__ float ns_lds[IT][ND];
    const int tid = threadIdx.x;
    for (int t = tid; t < IT * ND; t += 256) {
        ns_lds[t / ND][t % ND] = ns[(size_t)(b * NN + i0 + t / ND) * ND + (t % ND)];
    }
    __syncthreads();
    const int h = tid;
    float accP[IT], accQ[IT];
    const float bias = be1[e * NH + h];
#pragma unroll
    for (int m = 0; m < IT; m++) { accP[m] = 0.f; accQ[m] = bias; }
    const float* W1 = We1 + (size_t)e * 2 * ND * NH + h;
    for (int d = 0; d < ND; d++) {
        const float w1 = W1[(size_t)d * NH];
        const float w2 = W1[(size_t)(ND + d) * NH];
#pragma unroll
        for (int m = 0; m < IT; m++) {
            accP[m] = fmaf(ns_lds[m][d], w1, accP[m]);
            accQ[m] = fmaf(ns_lds[m][d], w2, accQ[m]);
        }
    }
#pragma unroll
    for (int m = 0; m < IT; m++) {
        const size_t idx = ((size_t)((b * NE + e) * NN) + i0 + m) * NH + h;
        P[idx] = accP[m];
        Q[idx] = accQ[m];
    }
}

// ---------------- Kernel 2: bucketed masked layer-2 + aggregate + decoder ----------------
// One block per (b, j) target node. 256 threads.
#define MT 32
__global__ __launch_bounds__(256) void edge_kernel(
    const float* __restrict__ ns,
    const float* __restrict__ edges,
    const float* __restrict__ P,
    const float* __restrict__ Q,
    const float* __restrict__ We2,
    const float* __restrict__ be2,
    const float* __restrict__ Wd1,
    const float* __restrict__ bd1,
    const float* __restrict__ Wd2,
    const float* __restrict__ bd2,
    float* __restrict__ out)
{
    const int j = blockIdx.x & (NN - 1);
    const int b = blockIdx.x >> 7;
    const int tid = threadIdx.x;
    const int lane = tid & 63;
    const int wave = tid >> 6;
    const int nt = tid & 31;   // col group: cols nt*8 .. nt*8+7
    const int mg = tid >> 5;   // row group: rows mg*4 .. mg*4+3

    __shared__ __align__(16) float At[NH][MT + 4];  // [k][m], padded to 36 for 16B-aligned float4
    __shared__ float part[8][NH];                   // per-mg partial aggr (deterministic, no atomics)
    __shared__ float aggr[NH];
    __shared__ float o1s[NH];
    __shared__ int lists[NE][NN];
    __shared__ int e_of[NN];
    __shared__ int cnt[NE];

    for (int t = tid; t < 8 * NH; t += 256) part[t >> 8][t & 255] = 0.f;

    // classify sources by edge type (edges are exact one-hot floats)
    if (tid < NN) {
        const float* ed = edges + ((size_t)(b * NN + tid) * NN + j) * 4;
        int e = -1;
        if (ed[1] > 0.5f) e = 0;
        else if (ed[2] > 0.5f) e = 1;
        else if (ed[3] > 0.5f) e = 2;
        e_of[tid] = e;
    }
    __syncthreads();
    if (tid == 0) {  // deterministic serial bucket build (128 iters, one-time)
        int c0 = 0, c1 = 0, c2 = 0;
        for (int i = 0; i < NN; i++) {
            const int e = e_of[i];
            if (e == 0) lists[0][c0++] = i;
            else if (e == 1) lists[1][c1++] = i;
            else if (e == 2) lists[2][c2++] = i;
        }
        cnt[0] = c0; cnt[1] = c1; cnt[2] = c2;
    }
    __syncthreads();

    for (int e = 0; e < NE; e++) {
        const int ce = cnt[e];
        const float* Pb = P + (size_t)(b * NE + e) * NN * NH;
        const float* Qj = Q + ((size_t)(b * NE + e) * NN + j) * NH;
        const float* W2 = We2 + (size_t)e * NH * NH + nt * 8;
        const float* b2 = be2 + e * NH;
        for (int t0 = 0; t0 < ce; t0 += MT) {
            __syncthreads();  // previous tile's readers done
            // fill A-tile: h1 rows = relu(P_i + Q_j)
            for (int r = wave; r < MT; r += 4) {
                const int idx = t0 + r;
                const int ir = lists[e][idx < ce ? idx : t0];  // padded rows masked later
                const float* Pr = Pb + (size_t)ir * NH;
#pragma unroll
                for (int kk = 0; kk < 4; kk++) {
                    const int k = kk * 64 + lane;
                    At[k][r] = fmaxf(Pr[k] + Qj[k], 0.f);
                }
            }
            __syncthreads();
            // register-tiled GEMM: acc[4m][8n], A from LDS (float4), W streamed from L2
            float acc[4][8];
#pragma unroll
            for (int a = 0; a < 4; a++)
#pragma unroll
                for (int c = 0; c < 8; c++) acc[a][c] = 0.f;
#pragma unroll 4
            for (int k = 0; k < NH; k++) {
                const float4 a4 = *(const float4*)&At[k][mg * 4];
                const float4 w0 = *(const float4*)&W2[(size_t)k * NH];
                const float4 w1 = *(const float4*)&W2[(size_t)k * NH + 4];
                const float av[4] = {a4.x, a4.y, a4.z, a4.w};
                const float wv[8] = {w0.x, w0.y, w0.z, w0.w, w1.x, w1.y, w1.z, w1.w};
#pragma unroll
                for (int a = 0; a < 4; a++)
#pragma unroll
                    for (int c = 0; c < 8; c++)
                        acc[a][c] = fmaf(av[a], wv[c], acc[a][c]);
            }
            // per-row bias+relu, masked sum into this thread's exclusive partial slot
#pragma unroll
            for (int c = 0; c < 8; c++) {
                const int col = nt * 8 + c;
                const float bb = b2[col];
                float s = 0.f;
#pragma unroll
                for (int a = 0; a < 4; a++) {
                    if (t0 + mg * 4 + a < ce)
                        s += fmaxf(acc[a][c] + bb, 0.f);
                }
                part[mg][col] += s;
            }
        }
    }
    __syncthreads();
    // deterministic 8-way reduce of partials
    {
        float ag = 0.f;
#pragma unroll
        for (int g = 0; g < 8; g++) ag += part[g][tid];
        aggr[tid] = ag;
    }
    __syncthreads();
    // fused decoder layer 1: dec_in = [ns[b,j,:], aggr] (320) -> relu(.Wd1 + bd1) (256)
    {
        float a1 = bd1[tid];
        const float* nsr = ns + (size_t)(b * NN + j) * ND;
        for (int c = 0; c < ND; c++)
            a1 = fmaf(nsr[c], Wd1[(size_t)c * NH + tid], a1);
        for (int c = 0; c < NH; c++)
            a1 = fmaf(aggr[c], Wd1[(size_t)(ND + c) * NH + tid], a1);
        o1s[tid] = fmaxf(a1, 0.f);
    }
    __syncthreads();
    // decoder layer 2: (256) -> relu(.Wd2 + bd2) (64)
    if (tid < NOUT) {
        float a2 = bd2[tid];
        for (int h = 0; h < NH; h++)
            a2 = fmaf(o1s[h], Wd2[(size_t)h * NOUT + tid], a2);
        out[(size_t)(b * NN + j) * NOUT + tid] = fmaxf(a2, 0.f);
    }
}

extern "C" void kernel_launch(void* const* d_in, const int* in_sizes, int n_in,
                              void* d_out, int out_size, void* d_ws, size_t ws_size,
                              hipStream_t stream)
{
    const float* ns    = (const float*)d_in[0];
    const float* edges = (const float*)d_in[1];
    const float* We1   = (const float*)d_in[2];
    const float* be1   = (const float*)d_in[3];
    const float* We2   = (const float*)d_in[4];
    const float* be2   = (const float*)d_in[5];
    const float* Wd1   = (const float*)d_in[6];
    const float* bd1   = (const float*)d_in[7];
    const float* Wd2   = (const float*)d_in[8];
    const float* bd2   = (const float*)d_in[9];
    float* outp = (float*)d_out;
    float* P = (float*)d_ws;                           // B*E*N*H floats
    float* Q = P + (size_t)NB * NE * NN * NH;          // B*E*N*H floats  (total 6.3 MB)

    hipLaunchKernelGGL(pq_kernel, dim3(NB * NE * (NN / IT)), dim3(256), 0, stream,
                       ns, We1, be1, P, Q);
    hipLaunchKernelGGL(edge_kernel, dim3(NB * NN), dim3(256), 0, stream,
                       ns, edges, P, Q, We2, be2, Wd1, bd1, Wd2, bd2, outp);
}

// Round 2
// 154.687 us; speedup vs baseline: 2.6591x; 2.6591x over previous
//
#include <hip/hip_runtime.h>

#define NB 8
#define NN 128
#define ND 64
#define NE 3
#define NH 256
#define NOUT 64
#define MT 32

typedef short bf16x8_t __attribute__((ext_vector_type(8)));
typedef float f32x4_t __attribute__((ext_vector_type(4)));

static __device__ __forceinline__ unsigned short f2bf(float f) {
    unsigned u = __float_as_uint(f);
    u += 0x7FFFu + ((u >> 16) & 1u);
    return (unsigned short)(u >> 16);
}

// ---------------- Kernel 0: We2t[e][n][k] = bf16(We2[e][k][n]) ----------------
__global__ __launch_bounds__(256) void prep_kernel(const float* __restrict__ We2,
                                                   unsigned short* __restrict__ We2t)
{
    const int e  = blockIdx.x >> 6;
    const int kt = (blockIdx.x >> 3) & 7;
    const int nt = blockIdx.x & 7;
    __shared__ float tile[32][33];
    const int t = threadIdx.x;
    const int tx = t & 31, ty = t >> 5;      // ty 0..7
    const float* src = We2 + ((size_t)e * NH + kt * 32) * NH + nt * 32;
#pragma unroll
    for (int s = 0; s < 4; s++) {
        const int k = ty + 8 * s;
        tile[k][tx] = src[(size_t)k * NH + tx];
    }
    __syncthreads();
    unsigned short* dst = We2t + ((size_t)e * NH + nt * 32) * NH + kt * 32;
#pragma unroll
    for (int s = 0; s < 4; s++) {
        const int n = ty + 8 * s;
        dst[(size_t)n * NH + tx] = f2bf(tile[tx][n]);
    }
}

// ---------------- Kernel 1: P/Q precompute (fp32, unchanged) ----------------
#define IT 16
__global__ __launch_bounds__(256) void pq_kernel(
    const float* __restrict__ ns,
    const float* __restrict__ We1,
    const float* __restrict__ be1,
    float* __restrict__ P, float* __restrict__ Q)
{
    const int blk = blockIdx.x;
    const int itile = blk & 7;
    const int e = (blk >> 3) % NE;
    const int b = blk / (8 * NE);
    const int i0 = itile * IT;
    __shared__ float ns_lds[IT][ND];
    const int tid = threadIdx.x;
    for (int t = tid; t < IT * ND; t += 256)
        ns_lds[t / ND][t % ND] = ns[(size_t)(b * NN + i0 + t / ND) * ND + (t % ND)];
    __syncthreads();
    const int h = tid;
    float accP[IT], accQ[IT];
    const float bias = be1[e * NH + h];
#pragma unroll
    for (int m = 0; m < IT; m++) { accP[m] = 0.f; accQ[m] = bias; }
    const float* W1 = We1 + (size_t)e * 2 * ND * NH + h;
    for (int d = 0; d < ND; d++) {
        const float w1 = W1[(size_t)d * NH];
        const float w2 = W1[(size_t)(ND + d) * NH];
#pragma unroll
        for (int m = 0; m < IT; m++) {
            accP[m] = fmaf(ns_lds[m][d], w1, accP[m]);
            accQ[m] = fmaf(ns_lds[m][d], w2, accQ[m]);
        }
    }
#pragma unroll
    for (int m = 0; m < IT; m++) {
        const size_t idx = ((size_t)((b * NE + e) * NN) + i0 + m) * NH + h;
        P[idx] = accP[m];
        Q[idx] = accQ[m];
    }
}

// ---------------- Kernel 2: MFMA layer-2 + aggregate + decoder ----------------
__global__ __launch_bounds__(256) void edge_kernel(
    const float* __restrict__ ns,
    const float* __restrict__ edges,
    const float* __restrict__ P,
    const float* __restrict__ Q,
    const unsigned short* __restrict__ We2t,
    const float* __restrict__ be2,
    const float* __restrict__ Wd1,
    const float* __restrict__ bd1,
    const float* __restrict__ Wd2,
    const float* __restrict__ bd2,
    float* __restrict__ out)
{
    const int j = blockIdx.x & (NN - 1);
    const int b = blockIdx.x >> 7;
    const int tid = threadIdx.x;
    const int lane = tid & 63;
    const int wave = tid >> 6;

    __shared__ __align__(16) char At[MT * 512];   // 32 rows x 256 bf16, XOR-swizzled
    __shared__ float qj[NH];
    __shared__ float aggr[NH];
    __shared__ float o1s[NH];
    __shared__ int lists[NE][NN];
    __shared__ unsigned long long wmask[2][NE];
    __shared__ int cnt[NE];

    // ---- bucket build via per-wave ballots (waves 0,1 cover i = tid) ----
    int ecls = -1;
    if (tid < 128) {
        const float* ed = edges + ((size_t)(b * NN + tid) * NN + j) * 4;
        if (ed[1] > 0.5f) ecls = 0;
        else if (ed[2] > 0.5f) ecls = 1;
        else if (ed[3] > 0.5f) ecls = 2;
#pragma unroll
        for (int ee = 0; ee < NE; ee++) {
            unsigned long long m = __ballot(ecls == ee);
            if (lane == 0) wmask[wave][ee] = m;
        }
    }
    __syncthreads();
    if (tid < 128 && ecls >= 0) {
        const unsigned long long lower = (1ull << lane) - 1ull;
        int pos = __popcll(wmask[wave][ecls] & lower);
        if (wave == 1) pos += __popcll(wmask[0][ecls]);
        lists[ecls][pos] = tid;
    }
    if (tid < NE) cnt[tid] = __popcll(wmask[0][tid]) + __popcll(wmask[1][tid]);
    __syncthreads();

    float rsum[4] = {0.f, 0.f, 0.f, 0.f};

    for (int e = 0; e < NE; e++) {
        const int ce = cnt[e];
        if (ce == 0) continue;
        qj[tid] = Q[(((size_t)b * NE + e) * NN + j) * NH + tid];
        float bb[4];
#pragma unroll
        for (int nf = 0; nf < 4; nf++)
            bb[nf] = be2[e * NH + wave * 64 + nf * 16 + (lane & 15)];
        const float* Pb = P + ((size_t)b * NE + e) * NN * NH;
        const unsigned short* Bt = We2t + (size_t)e * NH * NH;

        for (int t0 = 0; t0 < ce; t0 += MT) {
            __syncthreads();   // qj visible / previous tile's readers done
            // ---- stage A-tile: row r = relu(P_i + Q_j), bf16, swizzled ----
            {
                const int r = tid >> 3, p = tid & 7;
                const int rg = t0 + r;
                char* wbase = At + r * 512;
                const int swz = (r & 7) << 4;
                if (rg < ce) {
                    const int i = lists[e][rg];
                    const float* Pr = Pb + (size_t)i * NH + p * 32;
#pragma unroll
                    for (int q = 0; q < 4; q++) {
                        const int k = p * 32 + q * 8;
                        const float4 x0 = *(const float4*)(Pr + q * 8);
                        const float4 x1 = *(const float4*)(Pr + q * 8 + 4);
                        const float a0 = fmaxf(x0.x + qj[k + 0], 0.f);
                        const float a1 = fmaxf(x0.y + qj[k + 1], 0.f);
                        const float a2 = fmaxf(x0.z + qj[k + 2], 0.f);
                        const float a3 = fmaxf(x0.w + qj[k + 3], 0.f);
                        const float a4 = fmaxf(x1.x + qj[k + 4], 0.f);
                        const float a5 = fmaxf(x1.y + qj[k + 5], 0.f);
                        const float a6 = fmaxf(x1.z + qj[k + 6], 0.f);
                        const float a7 = fmaxf(x1.w + qj[k + 7], 0.f);
                        uint4 pk;
                        pk.x = (unsigned)f2bf(a0) | ((unsigned)f2bf(a1) << 16);
                        pk.y = (unsigned)f2bf(a2) | ((unsigned)f2bf(a3) << 16);
                        pk.z = (unsigned)f2bf(a4) | ((unsigned)f2bf(a5) << 16);
                        pk.w = (unsigned)f2bf(a6) | ((unsigned)f2bf(a7) << 16);
                        *(uint4*)(wbase + ((p * 64 + q * 16) ^ swz)) = pk;
                    }
                } else {
                    const uint4 z = {0u, 0u, 0u, 0u};
#pragma unroll
                    for (int q = 0; q < 4; q++)
                        *(uint4*)(wbase + ((p * 64 + q * 16) ^ swz)) = z;
                }
            }
            __syncthreads();
            // ---- MFMA: wave computes rows t0..t0+31 x cols wave*64..+63 ----
            f32x4_t acc[2][4];
            const f32x4_t z4 = {0.f, 0.f, 0.f, 0.f};
#pragma unroll
            for (int mf = 0; mf < 2; mf++)
#pragma unroll
                for (int nf = 0; nf < 4; nf++) acc[mf][nf] = z4;
#pragma unroll
            for (int kk = 0; kk < 8; kk++) {
                bf16x8_t af[2];
#pragma unroll
                for (int mf = 0; mf < 2; mf++) {
                    const int row = mf * 16 + (lane & 15);
                    const int off = (row * 512 + kk * 64 + (lane >> 4) * 16) ^ ((row & 7) << 4);
                    af[mf] = *(const bf16x8_t*)(At + off);
                }
#pragma unroll
                for (int nf = 0; nf < 4; nf++) {
                    const int n = wave * 64 + nf * 16 + (lane & 15);
                    const bf16x8_t bfr = *(const bf16x8_t*)(Bt + (size_t)n * NH + kk * 32 + (lane >> 4) * 8);
#pragma unroll
                    for (int mf = 0; mf < 2; mf++)
                        acc[mf][nf] = __builtin_amdgcn_mfma_f32_16x16x32_bf16(af[mf], bfr, acc[mf][nf], 0, 0, 0);
                }
            }
            // ---- epilogue: bias+relu+row-mask, accumulate column sums ----
#pragma unroll
            for (int mf = 0; mf < 2; mf++) {
#pragma unroll
                for (int r = 0; r < 4; r++) {
                    const int row = t0 + mf * 16 + (lane >> 4) * 4 + r;
                    if (row < ce) {
#pragma unroll
                        for (int nf = 0; nf < 4; nf++)
                            rsum[nf] += fmaxf(acc[mf][nf][r] + bb[nf], 0.f);
                    }
                }
            }
        }
    }
    // ---- reduce column sums across the 4 row-groups of each wave ----
#pragma unroll
    for (int nf = 0; nf < 4; nf++) {
        float v = rsum[nf];
        v += __shfl_xor(v, 16, 64);
        v += __shfl_xor(v, 32, 64);
        rsum[nf] = v;
    }
    if ((lane >> 4) == 0) {
#pragma unroll
        for (int nf = 0; nf < 4; nf++)
            aggr[wave * 64 + nf * 16 + lane] = rsum[nf];
    }
    __syncthreads();
    // ---- decoder layer 1: [ns, aggr](320) -> relu(.Wd1 + bd1)(256) ----
    {
        float a1 = bd1[tid];
        const float* nsr = ns + ((size_t)b * NN + j) * ND;
        for (int c = 0; c < ND; c++)
            a1 = fmaf(nsr[c], Wd1[(size_t)c * NH + tid], a1);
        for (int c = 0; c < NH; c++)
            a1 = fmaf(aggr[c], Wd1[(size_t)(ND + c) * NH + tid], a1);
        o1s[tid] = fmaxf(a1, 0.f);
    }
    __syncthreads();
    // ---- decoder layer 2: (256) -> relu(.Wd2 + bd2)(64) ----
    if (tid < NOUT) {
        float a2 = bd2[tid];
        for (int h = 0; h < NH; h++)
            a2 = fmaf(o1s[h], Wd2[(size_t)h * NOUT + tid], a2);
        out[((size_t)b * NN + j) * NOUT + tid] = fmaxf(a2, 0.f);
    }
}

extern "C" void kernel_launch(void* const* d_in, const int* in_sizes, int n_in,
                              void* d_out, int out_size, void* d_ws, size_t ws_size,
                              hipStream_t stream)
{
    const float* ns    = (const float*)d_in[0];
    const float* edges = (const float*)d_in[1];
    const float* We1   = (const float*)d_in[2];
    const float* be1   = (const float*)d_in[3];
    const float* We2   = (const float*)d_in[4];
    const float* be2   = (const float*)d_in[5];
    const float* Wd1   = (const float*)d_in[6];
    const float* bd1   = (const float*)d_in[7];
    const float* Wd2   = (const float*)d_in[8];
    const float* bd2   = (const float*)d_in[9];
    float* outp = (float*)d_out;

    float* P = (float*)d_ws;                                  // 3 MB
    float* Q = P + (size_t)NB * NE * NN * NH;                 // 3 MB
    unsigned short* We2t = (unsigned short*)(Q + (size_t)NB * NE * NN * NH); // 384 KB

    hipLaunchKernelGGL(prep_kernel, dim3(NE * 64), dim3(256), 0, stream, We2, We2t);
    hipLaunchKernelGGL(pq_kernel, dim3(NB * NE * (NN / IT)), dim3(256), 0, stream,
                       ns, We1, be1, P, Q);
    hipLaunchKernelGGL(edge_kernel, dim3(NB * NN), dim3(256), 0, stream,
                       ns, edges, P, Q, We2t, be2, Wd1, bd1, Wd2, bd2, outp);
}

// Round 4
// 125.038 us; speedup vs baseline: 3.2897x; 1.2371x over previous
//
#include <hip/hip_runtime.h>

#define NB 8
#define NN 128
#define ND 64
#define NE 3
#define NH 256
#define NOUT 64

typedef short bf16x8_t __attribute__((ext_vector_type(8)));
typedef float f32x4_t __attribute__((ext_vector_type(4)));

static __device__ __forceinline__ unsigned short f2bf(float f) {
    unsigned u = __float_as_uint(f);
    u += 0x7FFFu + ((u >> 16) & 1u);
    return (unsigned short)(u >> 16);
}
static __device__ __forceinline__ unsigned pk2bf(float a, float b) {
    return (unsigned)f2bf(a) | ((unsigned)f2bf(b) << 16);
}
static __device__ __forceinline__ float bflo(unsigned u) { return __uint_as_float(u << 16); }
static __device__ __forceinline__ float bfhi(unsigned u) { return __uint_as_float(u & 0xffff0000u); }

// ---------------- Kernel 0: weight prep ----------------
// blocks 0..191:   We2t[e][n][k] = bf16(We2[e][k][n])        (3 x 256x256)
// blocks 192..271: Wd1t[n][k]    = Wd1[k][n]   fp32          (320x256 -> 256x320)
// blocks 272..287: Wd2t[n][k]    = Wd2[k][n]   fp32          (256x64  -> 64x256)
__global__ __launch_bounds__(256) void prep_kernel(
    const float* __restrict__ We2, const float* __restrict__ Wd1,
    const float* __restrict__ Wd2,
    unsigned short* __restrict__ We2t, float* __restrict__ Wd1t,
    float* __restrict__ Wd2t)
{
    __shared__ float tile[32][33];
    const int t = threadIdx.x;
    const int tx = t & 31, ty = t >> 5;   // ty 0..7
    const int blk = blockIdx.x;
    const float* src; int srcld;
    if (blk < 192) {
        const int e = blk >> 6, kt = (blk >> 3) & 7, nt = blk & 7;
        src = We2 + ((size_t)e * NH + kt * 32) * NH + nt * 32; srcld = NH;
#pragma unroll
        for (int s = 0; s < 4; s++) { const int k = ty + 8 * s; tile[k][tx] = src[(size_t)k * srcld + tx]; }
        __syncthreads();
        unsigned short* dst = We2t + ((size_t)e * NH + nt * 32) * NH + kt * 32;
#pragma unroll
        for (int s = 0; s < 4; s++) { const int n = ty + 8 * s; dst[(size_t)n * NH + tx] = f2bf(tile[tx][n]); }
    } else if (blk < 272) {
        const int tt = blk - 192, kt = tt >> 3, nt = tt & 7;   // kt 0..9, nt 0..7
        src = Wd1 + ((size_t)kt * 32) * NH + nt * 32; srcld = NH;
#pragma unroll
        for (int s = 0; s < 4; s++) { const int k = ty + 8 * s; tile[k][tx] = src[(size_t)k * srcld + tx]; }
        __syncthreads();
        float* dst = Wd1t + ((size_t)(nt * 32)) * 320 + kt * 32;
#pragma unroll
        for (int s = 0; s < 4; s++) { const int n = ty + 8 * s; dst[(size_t)n * 320 + tx] = tile[tx][n]; }
    } else {
        const int tt = blk - 272, kt = tt >> 1, nt = tt & 1;   // kt 0..7, nt 0..1
        src = Wd2 + ((size_t)kt * 32) * NOUT + nt * 32; srcld = NOUT;
#pragma unroll
        for (int s = 0; s < 4; s++) { const int k = ty + 8 * s; tile[k][tx] = src[(size_t)k * srcld + tx]; }
        __syncthreads();
        float* dst = Wd2t + ((size_t)(nt * 32)) * NH + kt * 32;
#pragma unroll
        for (int s = 0; s < 4; s++) { const int n = ty + 8 * s; dst[(size_t)n * NH + tx] = tile[tx][n]; }
    }
}

// ---------------- Kernel 1: P/Q precompute -> bf16 ----------------
#define IT 16
__global__ __launch_bounds__(256) void pq_kernel(
    const float* __restrict__ ns,
    const float* __restrict__ We1,
    const float* __restrict__ be1,
    unsigned short* __restrict__ P, unsigned short* __restrict__ Q)
{
    const int blk = blockIdx.x;
    const int itile = blk & 7;
    const int e = (blk >> 3) % NE;
    const int b = blk / (8 * NE);
    const int i0 = itile * IT;
    __shared__ float ns_lds[IT][ND];
    const int tid = threadIdx.x;
    for (int t = tid; t < IT * ND; t += 256)
        ns_lds[t / ND][t % ND] = ns[(size_t)(b * NN + i0 + t / ND) * ND + (t % ND)];
    __syncthreads();
    const int h = tid;
    float accP[IT], accQ[IT];
    const float bias = be1[e * NH + h];
#pragma unroll
    for (int m = 0; m < IT; m++) { accP[m] = 0.f; accQ[m] = bias; }
    const float* W1 = We1 + (size_t)e * 2 * ND * NH + h;
    for (int d = 0; d < ND; d++) {
        const float w1 = W1[(size_t)d * NH];
        const float w2 = W1[(size_t)(ND + d) * NH];
#pragma unroll
        for (int m = 0; m < IT; m++) {
            accP[m] = fmaf(ns_lds[m][d], w1, accP[m]);
            accQ[m] = fmaf(ns_lds[m][d], w2, accQ[m]);
        }
    }
#pragma unroll
    for (int m = 0; m < IT; m++) {
        const size_t idx = ((size_t)((b * NE + e) * NN) + i0 + m) * NH + h;
        P[idx] = f2bf(accP[m]);
        Q[idx] = f2bf(accQ[m]);
    }
}

// ---------------- Kernel 2: per (b, j-pair) MFMA + aggregate + decoder ----------------
__global__ __launch_bounds__(256) void edge_kernel(
    const float* __restrict__ ns,
    const float* __restrict__ edges,
    const unsigned short* __restrict__ Pbf,
    const unsigned short* __restrict__ Qbf,
    const unsigned short* __restrict__ We2t,
    const float* __restrict__ be2,
    const float* __restrict__ Wd1t,
    const float* __restrict__ bd1,
    const float* __restrict__ Wd2t,
    const float* __restrict__ bd2,
    float* __restrict__ out)
{
    const int b  = blockIdx.x >> 6;
    const int j0 = (blockIdx.x & 63) << 1;
    const int tid = threadIdx.x;
    const int lane = tid & 63;
    const int wave = tid >> 6;

    __shared__ __align__(16) char At[128 * 512];   // 2 jl x 64 rows x 256 bf16, swizzled
    __shared__ float qjs[2][NH];
    __shared__ int lists[NE][2][NN];
    __shared__ int cnt[NE][2];
    __shared__ unsigned long long wm[2][NE];
    __shared__ float aggr[2][NH];
    __shared__ float o1s[2][NH];
    __shared__ float nsr[2][ND];

    // ---- bucket build: 2 target nodes, waves 0-1 classify 128 sources ----
    for (int jl = 0; jl < 2; jl++) {
        int ecls = -1;
        if (tid < 128) {
            const float4 ev = *(const float4*)(edges + ((size_t)(b * NN + tid) * NN + j0 + jl) * 4);
            ecls = ev.y > 0.5f ? 0 : (ev.z > 0.5f ? 1 : (ev.w > 0.5f ? 2 : -1));
#pragma unroll
            for (int ee = 0; ee < NE; ee++) {
                unsigned long long m = __ballot(ecls == ee);
                if (lane == 0) wm[wave][ee] = m;
            }
        }
        __syncthreads();
        if (tid < 128 && ecls >= 0) {
            const unsigned long long lower = (1ull << lane) - 1ull;
            int pos = __popcll(wm[wave][ecls] & lower);
            if (wave == 1) pos += __popcll(wm[0][ecls]);
            lists[ecls][jl][pos] = tid;
        }
        if (tid < NE) cnt[tid][jl] = __popcll(wm[0][tid]) + __popcll(wm[1][tid]);
        __syncthreads();
    }

    float rsum[2][4] = {{0.f, 0.f, 0.f, 0.f}, {0.f, 0.f, 0.f, 0.f}};

    for (int e = 0; e < NE; e++) {
        const int ce0 = cnt[e][0], ce1 = cnt[e][1];
        const int cemax = ce0 > ce1 ? ce0 : ce1;
        if (cemax == 0) continue;
        {   // qjs: bf16 -> f32
            const int jl = tid >> 7, k2 = (tid & 127) * 2;
            const unsigned u = *(const unsigned*)(Qbf + ((size_t)(b * NE + e) * NN + j0 + jl) * NH + k2);
            qjs[jl][k2] = bflo(u);
            qjs[jl][k2 + 1] = bfhi(u);
        }
        float bb[4];
#pragma unroll
        for (int nf = 0; nf < 4; nf++)
            bb[nf] = be2[e * NH + wave * 64 + nf * 16 + (lane & 15)];
        const unsigned short* Bt = We2t + (size_t)e * NH * NH;
        const unsigned short* Pb = Pbf + (size_t)(b * NE + e) * NN * NH;

        for (int c64 = 0; c64 < cemax; c64 += 64) {
            __syncthreads();   // qjs visible / previous tile's readers done
            {   // ---- stage up to 128 rows (2 jl x 64): relu(P_i + Q_j) -> bf16, swizzled ----
                const int r = tid >> 1, h = tid & 1;
                const int jl = r >> 6, rr = r & 63;
                const int ce = jl ? ce1 : ce0;
                const int g = c64 + rr;
                if (g < ce) {
                    const int i = lists[e][jl][g];
                    const unsigned short* Pr = Pb + (size_t)i * NH + h * 128;
                    const float* qr = &qjs[jl][h * 128];
                    char* wb = At + (jl * 64 + rr) * 512;
                    const int swz = (rr & 7) << 4;
                    const int kb = h * 256;
#pragma unroll
                    for (int q = 0; q < 16; q++) {
                        const uint4 pv = *(const uint4*)(Pr + q * 8);
                        const float4 q0 = *(const float4*)(qr + q * 8);
                        const float4 q1 = *(const float4*)(qr + q * 8 + 4);
                        const float f0 = fmaxf(bflo(pv.x) + q0.x, 0.f);
                        const float f1 = fmaxf(bfhi(pv.x) + q0.y, 0.f);
                        const float f2 = fmaxf(bflo(pv.y) + q0.z, 0.f);
                        const float f3 = fmaxf(bfhi(pv.y) + q0.w, 0.f);
                        const float f4 = fmaxf(bflo(pv.z) + q1.x, 0.f);
                        const float f5 = fmaxf(bfhi(pv.z) + q1.y, 0.f);
                        const float f6 = fmaxf(bflo(pv.w) + q1.z, 0.f);
                        const float f7 = fmaxf(bfhi(pv.w) + q1.w, 0.f);
                        uint4 pk;
                        pk.x = pk2bf(f0, f1); pk.y = pk2bf(f2, f3);
                        pk.z = pk2bf(f4, f5); pk.w = pk2bf(f6, f7);
                        *(uint4*)(wb + ((kb + q * 16) ^ swz)) = pk;
                    }
                }
            }
            __syncthreads();
            // ---- mf tiles of 16 rows; B-frags shared across both jl ----
            for (int mf = 0; mf < 4; mf++) {
                const int m0 = c64 + mf * 16;
                if (m0 >= cemax) break;            // block-uniform
                f32x4_t acc0[4], acc1[4];
                const f32x4_t z4 = {0.f, 0.f, 0.f, 0.f};
#pragma unroll
                for (int nf = 0; nf < 4; nf++) { acc0[nf] = z4; acc1[nf] = z4; }
#pragma unroll
                for (int kk = 0; kk < 8; kk++) {
                    const int lr0 = mf * 16 + (lane & 15);
                    const int koff = (kk * 64 + (lane >> 4) * 16);
                    const int sw = (lr0 & 7) << 4;
                    const bf16x8_t af0 = *(const bf16x8_t*)(At + ((lr0 * 512 + koff) ^ sw));
                    const bf16x8_t af1 = *(const bf16x8_t*)(At + (((lr0 + 64) * 512 + koff) ^ sw));
#pragma unroll
                    for (int nf = 0; nf < 4; nf++) {
                        const int n = wave * 64 + nf * 16 + (lane & 15);
                        const bf16x8_t bfr = *(const bf16x8_t*)(Bt + (size_t)n * NH + kk * 32 + (lane >> 4) * 8);
                        acc0[nf] = __builtin_amdgcn_mfma_f32_16x16x32_bf16(af0, bfr, acc0[nf], 0, 0, 0);
                        acc1[nf] = __builtin_amdgcn_mfma_f32_16x16x32_bf16(af1, bfr, acc1[nf], 0, 0, 0);
                    }
                }
                // ---- epilogue: bias+relu+mask, accumulate column sums ----
#pragma unroll
                for (int r = 0; r < 4; r++) {
                    const int g = m0 + (lane >> 4) * 4 + r;
                    if (g < ce0) {
#pragma unroll
                        for (int nf = 0; nf < 4; nf++)
                            rsum[0][nf] += fmaxf(acc0[nf][r] + bb[nf], 0.f);
                    }
                    if (g < ce1) {
#pragma unroll
                        for (int nf = 0; nf < 4; nf++)
                            rsum[1][nf] += fmaxf(acc1[nf][r] + bb[nf], 0.f);
                    }
                }
            }
        }
    }

    // ---- reduce column sums over the 4 row-groups; stage ns rows ----
#pragma unroll
    for (int jl = 0; jl < 2; jl++)
#pragma unroll
        for (int nf = 0; nf < 4; nf++) {
            float v = rsum[jl][nf];
            v += __shfl_xor(v, 16, 64);
            v += __shfl_xor(v, 32, 64);
            rsum[jl][nf] = v;
        }
    if ((lane >> 4) == 0) {
#pragma unroll
        for (int jl = 0; jl < 2; jl++)
#pragma unroll
            for (int nf = 0; nf < 4; nf++)
                aggr[jl][wave * 64 + nf * 16 + lane] = rsum[jl][nf];
    }
    if (tid < 128) nsr[tid >> 6][tid & 63] = ns[((size_t)b * NN + j0 + (tid >> 6)) * ND + (tid & 63)];
    __syncthreads();

    // ---- decoder layer 1: [ns(64), aggr(256)] -> relu(.Wd1 + bd1), both jl share W ----
    {
        const int col = tid;
        float a0 = bd1[col], a1 = a0;
        const float* W = Wd1t + (size_t)col * 320;
#pragma unroll 4
        for (int cb = 0; cb < 16; cb++) {
            const float4 w = *(const float4*)(W + cb * 4);
            const float4 x0 = *(const float4*)(&nsr[0][cb * 4]);
            const float4 x1 = *(const float4*)(&nsr[1][cb * 4]);
            a0 = fmaf(w.x, x0.x, fmaf(w.y, x0.y, fmaf(w.z, x0.z, fmaf(w.w, x0.w, a0))));
            a1 = fmaf(w.x, x1.x, fmaf(w.y, x1.y, fmaf(w.z, x1.z, fmaf(w.w, x1.w, a1))));
        }
#pragma unroll 4
        for (int cb = 0; cb < 64; cb++) {
            const float4 w = *(const float4*)(W + 64 + cb * 4);
            const float4 x0 = *(const float4*)(&aggr[0][cb * 4]);
            const float4 x1 = *(const float4*)(&aggr[1][cb * 4]);
            a0 = fmaf(w.x, x0.x, fmaf(w.y, x0.y, fmaf(w.z, x0.z, fmaf(w.w, x0.w, a0))));
            a1 = fmaf(w.x, x1.x, fmaf(w.y, x1.y, fmaf(w.z, x1.z, fmaf(w.w, x1.w, a1))));
        }
        o1s[0][col] = fmaxf(a0, 0.f);
        o1s[1][col] = fmaxf(a1, 0.f);
    }
    __syncthreads();
    // ---- decoder layer 2: (256) -> relu(.Wd2 + bd2)(64) ----
    if (tid < 128) {
        const int jl = tid >> 6, col = tid & 63;
        float a2 = bd2[col];
        const float* W2 = Wd2t + (size_t)col * NH;
#pragma unroll 4
        for (int hb = 0; hb < 64; hb++) {
            const float4 w = *(const float4*)(W2 + hb * 4);
            const float4 x = *(const float4*)(&o1s[jl][hb * 4]);
            a2 = fmaf(w.x, x.x, fmaf(w.y, x.y, fmaf(w.z, x.z, fmaf(w.w, x.w, a2))));
        }
        out[((size_t)b * NN + j0 + jl) * NOUT + col] = fmaxf(a2, 0.f);
    }
}

extern "C" void kernel_launch(void* const* d_in, const int* in_sizes, int n_in,
                              void* d_out, int out_size, void* d_ws, size_t ws_size,
                              hipStream_t stream)
{
    const float* ns    = (const float*)d_in[0];
    const float* edges = (const float*)d_in[1];
    const float* We1   = (const float*)d_in[2];
    const float* be1   = (const float*)d_in[3];
    const float* We2   = (const float*)d_in[4];
    const float* be2   = (const float*)d_in[5];
    const float* Wd1   = (const float*)d_in[6];
    const float* bd1   = (const float*)d_in[7];
    const float* Wd2   = (const float*)d_in[8];
    const float* bd2   = (const float*)d_in[9];
    float* outp = (float*)d_out;

    // ws layout (3.75 MB total)
    unsigned short* Pbf  = (unsigned short*)d_ws;                 // 786432 elems
    unsigned short* Qbf  = Pbf + (size_t)NB * NE * NN * NH;       // 786432
    unsigned short* We2t = Qbf + (size_t)NB * NE * NN * NH;       // 196608
    float* Wd1t = (float*)(We2t + (size_t)NE * NH * NH);          // 81920 f32
    float* Wd2t = Wd1t + 256 * 320;                               // 16384 f32

    hipLaunchKernelGGL(prep_kernel, dim3(288), dim3(256), 0, stream,
                       We2, Wd1, Wd2, We2t, Wd1t, Wd2t);
    hipLaunchKernelGGL(pq_kernel, dim3(NB * NE * (NN / IT)), dim3(256), 0, stream,
                       ns, We1, be1, Pbf, Qbf);
    hipLaunchKernelGGL(edge_kernel, dim3(NB * 64), dim3(256), 0, stream,
                       ns, edges, Pbf, Qbf, We2t, be2, Wd1t, bd1, Wd2t, bd2, outp);
}

// Round 5
// 120.187 us; speedup vs baseline: 3.4225x; 1.0404x over previous
//
#include <hip/hip_runtime.h>

#define NB 8
#define NN 128
#define ND 64
#define NE 3
#define NH 256
#define NOUT 64

typedef short bf16x8_t __attribute__((ext_vector_type(8)));
typedef float f32x4_t __attribute__((ext_vector_type(4)));

static __device__ __forceinline__ unsigned short f2bf(float f) {
    unsigned u = __float_as_uint(f);
    u += 0x7FFFu + ((u >> 16) & 1u);
    return (unsigned short)(u >> 16);
}
static __device__ __forceinline__ unsigned pk2bf(float a, float b) {
    return (unsigned)f2bf(a) | ((unsigned)f2bf(b) << 16);
}
static __device__ __forceinline__ float bflo(unsigned u) { return __uint_as_float(u << 16); }
static __device__ __forceinline__ float bfhi(unsigned u) { return __uint_as_float(u & 0xffff0000u); }

// ---------------- Kernel 0: weight prep (unchanged) ----------------
__global__ __launch_bounds__(256) void prep_kernel(
    const float* __restrict__ We2, const float* __restrict__ Wd1,
    const float* __restrict__ Wd2,
    unsigned short* __restrict__ We2t, float* __restrict__ Wd1t,
    float* __restrict__ Wd2t)
{
    __shared__ float tile[32][33];
    const int t = threadIdx.x;
    const int tx = t & 31, ty = t >> 5;
    const int blk = blockIdx.x;
    if (blk < 192) {
        const int e = blk >> 6, kt = (blk >> 3) & 7, nt = blk & 7;
        const float* src = We2 + ((size_t)e * NH + kt * 32) * NH + nt * 32;
#pragma unroll
        for (int s = 0; s < 4; s++) { const int k = ty + 8 * s; tile[k][tx] = src[(size_t)k * NH + tx]; }
        __syncthreads();
        unsigned short* dst = We2t + ((size_t)e * NH + nt * 32) * NH + kt * 32;
#pragma unroll
        for (int s = 0; s < 4; s++) { const int n = ty + 8 * s; dst[(size_t)n * NH + tx] = f2bf(tile[tx][n]); }
    } else if (blk < 272) {
        const int tt = blk - 192, kt = tt >> 3, nt = tt & 7;
        const float* src = Wd1 + ((size_t)kt * 32) * NH + nt * 32;
#pragma unroll
        for (int s = 0; s < 4; s++) { const int k = ty + 8 * s; tile[k][tx] = src[(size_t)k * NH + tx]; }
        __syncthreads();
        float* dst = Wd1t + ((size_t)(nt * 32)) * 320 + kt * 32;
#pragma unroll
        for (int s = 0; s < 4; s++) { const int n = ty + 8 * s; dst[(size_t)n * 320 + tx] = tile[tx][n]; }
    } else {
        const int tt = blk - 272, kt = tt >> 1, nt = tt & 1;
        const float* src = Wd2 + ((size_t)kt * 32) * NOUT + nt * 32;
#pragma unroll
        for (int s = 0; s < 4; s++) { const int k = ty + 8 * s; tile[k][tx] = src[(size_t)k * NOUT + tx]; }
        __syncthreads();
        float* dst = Wd2t + ((size_t)(nt * 32)) * NH + kt * 32;
#pragma unroll
        for (int s = 0; s < 4; s++) { const int n = ty + 8 * s; dst[(size_t)n * NH + tx] = tile[tx][n]; }
    }
}

// ---------------- Kernel 1: P/Q precompute -> bf16 (unchanged) ----------------
#define IT 16
__global__ __launch_bounds__(256) void pq_kernel(
    const float* __restrict__ ns,
    const float* __restrict__ We1,
    const float* __restrict__ be1,
    unsigned short* __restrict__ P, unsigned short* __restrict__ Q)
{
    const int blk = blockIdx.x;
    const int itile = blk & 7;
    const int e = (blk >> 3) % NE;
    const int b = blk / (8 * NE);
    const int i0 = itile * IT;
    __shared__ float ns_lds[IT][ND];
    const int tid = threadIdx.x;
    for (int t = tid; t < IT * ND; t += 256)
        ns_lds[t / ND][t % ND] = ns[(size_t)(b * NN + i0 + t / ND) * ND + (t % ND)];
    __syncthreads();
    const int h = tid;
    float accP[IT], accQ[IT];
    const float bias = be1[e * NH + h];
#pragma unroll
    for (int m = 0; m < IT; m++) { accP[m] = 0.f; accQ[m] = bias; }
    const float* W1 = We1 + (size_t)e * 2 * ND * NH + h;
    for (int d = 0; d < ND; d++) {
        const float w1 = W1[(size_t)d * NH];
        const float w2 = W1[(size_t)(ND + d) * NH];
#pragma unroll
        for (int m = 0; m < IT; m++) {
            accP[m] = fmaf(ns_lds[m][d], w1, accP[m]);
            accQ[m] = fmaf(ns_lds[m][d], w2, accQ[m]);
        }
    }
#pragma unroll
    for (int m = 0; m < IT; m++) {
        const size_t idx = ((size_t)((b * NE + e) * NN) + i0 + m) * NH + h;
        P[idx] = f2bf(accP[m]);
        Q[idx] = f2bf(accQ[m]);
    }
}

// ---------------- MFMA tile helper: NMF 16-row sub-tiles share each B-frag ----------------
template<int NMF>
static __device__ __forceinline__ void do_tile(
    const char* At, const unsigned short* Bt, int wave, int lane,
    int base, int ce0, int total, const float* bb, float* rs0, float* rs1)
{
    f32x4_t acc[NMF][4];
    const f32x4_t z4 = {0.f, 0.f, 0.f, 0.f};
#pragma unroll
    for (int mf = 0; mf < NMF; mf++)
#pragma unroll
        for (int nf = 0; nf < 4; nf++) acc[mf][nf] = z4;
#pragma unroll
    for (int kk = 0; kk < 8; kk++) {
        bf16x8_t af[NMF];
        const int koff = kk * 64 + (lane >> 4) * 16;
#pragma unroll
        for (int mf = 0; mf < NMF; mf++) {
            const int lr = mf * 16 + (lane & 15);
            af[mf] = *(const bf16x8_t*)(At + ((lr * 512 + koff) ^ ((lr & 7) << 4)));
        }
#pragma unroll
        for (int nf = 0; nf < 4; nf++) {
            const int n = wave * 64 + nf * 16 + (lane & 15);
            const bf16x8_t bfr = *(const bf16x8_t*)(Bt + (size_t)n * NH + kk * 32 + (lane >> 4) * 8);
#pragma unroll
            for (int mf = 0; mf < NMF; mf++)
                acc[mf][nf] = __builtin_amdgcn_mfma_f32_16x16x32_bf16(af[mf], bfr, acc[mf][nf], 0, 0, 0);
        }
    }
    // epilogue: bias+relu, route to jl0/jl1 partial by packed-row position
#pragma unroll
    for (int mf = 0; mf < NMF; mf++) {
#pragma unroll
        for (int r = 0; r < 4; r++) {
            const int g = base + mf * 16 + ((lane >> 4) << 2) + r;
            if (g < ce0) {
#pragma unroll
                for (int nf = 0; nf < 4; nf++)
                    rs0[nf] += fmaxf(acc[mf][nf][r] + bb[nf], 0.f);
            } else if (g < total) {
#pragma unroll
                for (int nf = 0; nf < 4; nf++)
                    rs1[nf] += fmaxf(acc[mf][nf][r] + bb[nf], 0.f);
            }
        }
    }
}

// ---------------- Kernel 2: per (b, j-pair), packed-row MFMA + decoder ----------------
__global__ __launch_bounds__(256) void edge_kernel(
    const float* __restrict__ ns,
    const float* __restrict__ edges,
    const unsigned short* __restrict__ Pbf,
    const unsigned short* __restrict__ Qbf,
    const unsigned short* __restrict__ We2t,
    const float* __restrict__ be2,
    const float* __restrict__ Wd1t,
    const float* __restrict__ bd1,
    const float* __restrict__ Wd2t,
    const float* __restrict__ bd2,
    float* __restrict__ out)
{
    const int b  = blockIdx.x >> 6;
    const int j0 = (blockIdx.x & 63) << 1;
    const int tid = threadIdx.x;
    const int lane = tid & 63;
    const int wave = tid >> 6;

    __shared__ __align__(16) char At[64 * 512];     // 64 packed rows x 256 bf16, swizzled (32 KB)
    __shared__ float qjs[2][NH];
    __shared__ int lists[NE][2 * NN];               // packed: [0,ce0) jl0, [ce0,ce0+ce1) jl1|0x80
    __shared__ unsigned long long wm0[2][NE], wm1[2][NE];
    __shared__ int cnt0s[NE], cnttot[NE];
    __shared__ int sched_e[14], sched_b[14], nsched_s;
    __shared__ float aggr[2][NH];
    __shared__ float o1s[2][NH];
    __shared__ float nsr[2][ND];

    // ---- single-pass bucket build for both target nodes ----
    int e0c = -1, e1c = -1;
    if (tid < 128) {
        const float4 ev0 = *(const float4*)(edges + ((size_t)(b * NN + tid) * NN + j0) * 4);
        const float4 ev1 = *(const float4*)(edges + ((size_t)(b * NN + tid) * NN + j0 + 1) * 4);
        e0c = ev0.y > 0.5f ? 0 : (ev0.z > 0.5f ? 1 : (ev0.w > 0.5f ? 2 : -1));
        e1c = ev1.y > 0.5f ? 0 : (ev1.z > 0.5f ? 1 : (ev1.w > 0.5f ? 2 : -1));
#pragma unroll
        for (int ee = 0; ee < NE; ee++) {
            unsigned long long m0 = __ballot(e0c == ee);
            unsigned long long m1 = __ballot(e1c == ee);
            if (lane == 0) { wm0[wave][ee] = m0; wm1[wave][ee] = m1; }
        }
    }
    __syncthreads();
    if (tid < 128) {
        const unsigned long long lower = (1ull << lane) - 1ull;
        if (e0c >= 0) {
            int pos = __popcll(wm0[wave][e0c] & lower);
            if (wave == 1) pos += __popcll(wm0[0][e0c]);
            lists[e0c][pos] = tid;
        }
        if (e1c >= 0) {
            const int c0 = __popcll(wm0[0][e1c]) + __popcll(wm0[1][e1c]);
            int pos = __popcll(wm1[wave][e1c] & lower);
            if (wave == 1) pos += __popcll(wm1[0][e1c]);
            lists[e1c][c0 + pos] = tid | 0x80;
        }
    }
    if (tid == 0) {
        int s = 0;
#pragma unroll
        for (int e = 0; e < NE; e++) {
            const int c0 = __popcll(wm0[0][e]) + __popcll(wm0[1][e]);
            const int c1 = __popcll(wm1[0][e]) + __popcll(wm1[1][e]);
            cnt0s[e] = c0; cnttot[e] = c0 + c1;
            for (int base = 0; base < c0 + c1; base += 64) { sched_e[s] = e; sched_b[s] = base; s++; }
        }
        nsched_s = s;
    }
    __syncthreads();

    const int nsched = nsched_s;
    float rs0[4] = {0.f, 0.f, 0.f, 0.f}, rs1[4] = {0.f, 0.f, 0.f, 0.f};
    int preve = -1;

    for (int s = 0; s < nsched; s++) {
        const int e = sched_e[s], base = sched_b[s];
        const int ce0 = cnt0s[e], total = cnttot[e];
        if (e != preve) {   // refresh Q_j rows for this edge type (block-uniform branch)
            const int jl = tid >> 7, k2 = (tid & 127) * 2;
            const unsigned u = *(const unsigned*)(Qbf + (((size_t)b * NE + e) * NN + j0 + jl) * NH + k2);
            qjs[jl][k2] = bflo(u);
            qjs[jl][k2 + 1] = bfhi(u);
            preve = e;
        }
        __syncthreads();   // prev tile's readers done + qjs visible
        {   // ---- stage 64 packed rows: relu(P_i + Q_j) -> bf16, swizzled; 4 thr/row ----
            const int r = tid >> 2, q = tid & 3;
            const int rows = min(64, total - base);
            const int pad16 = (rows + 15) & ~15;
            char* wb = At + r * 512;
            const int swz = (r & 7) << 4;
            if (r < rows) {
                const int v = lists[e][base + r];
                const int jl = v >> 7, i = v & 127;
                const unsigned short* Pr = Pbf + ((size_t)(b * NE + e) * NN + i) * NH + q * 64;
                const float* qr = &qjs[jl][q * 64];
#pragma unroll
                for (int t = 0; t < 8; t++) {
                    const uint4 pv = *(const uint4*)(Pr + t * 8);
                    const float4 q0 = *(const float4*)(qr + t * 8);
                    const float4 q1 = *(const float4*)(qr + t * 8 + 4);
                    const float f0 = fmaxf(bflo(pv.x) + q0.x, 0.f);
                    const float f1 = fmaxf(bfhi(pv.x) + q0.y, 0.f);
                    const float f2 = fmaxf(bflo(pv.y) + q0.z, 0.f);
                    const float f3 = fmaxf(bfhi(pv.y) + q0.w, 0.f);
                    const float f4 = fmaxf(bflo(pv.z) + q1.x, 0.f);
                    const float f5 = fmaxf(bfhi(pv.z) + q1.y, 0.f);
                    const float f6 = fmaxf(bflo(pv.w) + q1.z, 0.f);
                    const float f7 = fmaxf(bfhi(pv.w) + q1.w, 0.f);
                    uint4 pk;
                    pk.x = pk2bf(f0, f1); pk.y = pk2bf(f2, f3);
                    pk.z = pk2bf(f4, f5); pk.w = pk2bf(f6, f7);
                    *(uint4*)(wb + ((q * 128 + t * 16) ^ swz)) = pk;
                }
            } else if (r < pad16) {
                const uint4 z = {0u, 0u, 0u, 0u};
#pragma unroll
                for (int t = 0; t < 8; t++)
                    *(uint4*)(wb + ((q * 128 + t * 16) ^ swz)) = z;
            }
        }
        __syncthreads();
        float bb[4];
#pragma unroll
        for (int nf = 0; nf < 4; nf++)
            bb[nf] = be2[e * NH + wave * 64 + nf * 16 + (lane & 15)];
        const unsigned short* Bt = We2t + (size_t)e * NH * NH;
        const int rows = min(64, total - base);
        const int nmf = (rows + 15) >> 4;
        switch (nmf) {   // block-uniform
            case 1: do_tile<1>(At, Bt, wave, lane, base, ce0, total, bb, rs0, rs1); break;
            case 2: do_tile<2>(At, Bt, wave, lane, base, ce0, total, bb, rs0, rs1); break;
            case 3: do_tile<3>(At, Bt, wave, lane, base, ce0, total, bb, rs0, rs1); break;
            default: do_tile<4>(At, Bt, wave, lane, base, ce0, total, bb, rs0, rs1); break;
        }
    }

    // ---- reduce column sums over the 4 row-groups; stage ns rows ----
#pragma unroll
    for (int nf = 0; nf < 4; nf++) {
        float v0 = rs0[nf], v1 = rs1[nf];
        v0 += __shfl_xor(v0, 16, 64); v0 += __shfl_xor(v0, 32, 64);
        v1 += __shfl_xor(v1, 16, 64); v1 += __shfl_xor(v1, 32, 64);
        rs0[nf] = v0; rs1[nf] = v1;
    }
    if ((lane >> 4) == 0) {
#pragma unroll
        for (int nf = 0; nf < 4; nf++) {
            aggr[0][wave * 64 + nf * 16 + lane] = rs0[nf];
            aggr[1][wave * 64 + nf * 16 + lane] = rs1[nf];
        }
    }
    if (tid < 128) nsr[tid >> 6][tid & 63] = ns[((size_t)b * NN + j0 + (tid >> 6)) * ND + (tid & 63)];
    __syncthreads();

    // ---- decoder layer 1: [ns(64), aggr(256)] -> relu(.Wd1 + bd1), both jl share W ----
    {
        const int col = tid;
        float a0 = bd1[col], a1 = a0;
        const float* W = Wd1t + (size_t)col * 320;
#pragma unroll 4
        for (int cb = 0; cb < 16; cb++) {
            const float4 w = *(const float4*)(W + cb * 4);
            const float4 x0 = *(const float4*)(&nsr[0][cb * 4]);
            const float4 x1 = *(const float4*)(&nsr[1][cb * 4]);
            a0 = fmaf(w.x, x0.x, fmaf(w.y, x0.y, fmaf(w.z, x0.z, fmaf(w.w, x0.w, a0))));
            a1 = fmaf(w.x, x1.x, fmaf(w.y, x1.y, fmaf(w.z, x1.z, fmaf(w.w, x1.w, a1))));
        }
#pragma unroll 4
        for (int cb = 0; cb < 64; cb++) {
            const float4 w = *(const float4*)(W + 64 + cb * 4);
            const float4 x0 = *(const float4*)(&aggr[0][cb * 4]);
            const float4 x1 = *(const float4*)(&aggr[1][cb * 4]);
            a0 = fmaf(w.x, x0.x, fmaf(w.y, x0.y, fmaf(w.z, x0.z, fmaf(w.w, x0.w, a0))));
            a1 = fmaf(w.x, x1.x, fmaf(w.y, x1.y, fmaf(w.z, x1.z, fmaf(w.w, x1.w, a1))));
        }
        o1s[0][col] = fmaxf(a0, 0.f);
        o1s[1][col] = fmaxf(a1, 0.f);
    }
    __syncthreads();
    // ---- decoder layer 2: (256) -> relu(.Wd2 + bd2)(64) ----
    if (tid < 128) {
        const int jl = tid >> 6, col = tid & 63;
        float a2 = bd2[col];
        const float* W2 = Wd2t + (size_t)col * NH;
#pragma unroll 4
        for (int hb = 0; hb < 64; hb++) {
            const float4 w = *(const float4*)(W2 + hb * 4);
            const float4 x = *(const float4*)(&o1s[jl][hb * 4]);
            a2 = fmaf(w.x, x.x, fmaf(w.y, x.y, fmaf(w.z, x.z, fmaf(w.w, x.w, a2))));
        }
        out[((size_t)b * NN + j0 + jl) * NOUT + col] = fmaxf(a2, 0.f);
    }
}

extern "C" void kernel_launch(void* const* d_in, const int* in_sizes, int n_in,
                              void* d_out, int out_size, void* d_ws, size_t ws_size,
                              hipStream_t stream)
{
    const float* ns    = (const float*)d_in[0];
    const float* edges = (const float*)d_in[1];
    const float* We1   = (const float*)d_in[2];
    const float* be1   = (const float*)d_in[3];
    const float* We2   = (const float*)d_in[4];
    const float* be2   = (const float*)d_in[5];
    const float* Wd1   = (const float*)d_in[6];
    const float* bd1   = (const float*)d_in[7];
    const float* Wd2   = (const float*)d_in[8];
    const float* bd2   = (const float*)d_in[9];
    float* outp = (float*)d_out;

    unsigned short* Pbf  = (unsigned short*)d_ws;
    unsigned short* Qbf  = Pbf + (size_t)NB * NE * NN * NH;
    unsigned short* We2t = Qbf + (size_t)NB * NE * NN * NH;
    float* Wd1t = (float*)(We2t + (size_t)NE * NH * NH);
    float* Wd2t = Wd1t + 256 * 320;

    hipLaunchKernelGGL(prep_kernel, dim3(288), dim3(256), 0, stream,
                       We2, Wd1, Wd2, We2t, Wd1t, Wd2t);
    hipLaunchKernelGGL(pq_kernel, dim3(NB * NE * (NN / IT)), dim3(256), 0, stream,
                       ns, We1, be1, Pbf, Qbf);
    hipLaunchKernelGGL(edge_kernel, dim3(NB * 64), dim3(256), 0, stream,
                       ns, edges, Pbf, Qbf, We2t, be2, Wd1t, bd1, Wd2t, bd2, outp);
}